// Round 1
// baseline (277.531 us; speedup 1.0000x reference)
//
#include <hip/hip_runtime.h>

typedef short bfrag __attribute__((ext_vector_type(8)));   // 8 x bf16 (4 VGPRs)
typedef float facc  __attribute__((ext_vector_type(4)));   // MFMA accumulator
typedef unsigned short u16;
typedef unsigned int   u32;

#define LOG2E 1.4426950408889634f
#define MFMA(A,B,C) __builtin_amdgcn_mfma_f32_16x16x32_bf16((A),(B),(C),0,0,0)

// ---- LDS element offsets (u16 units) ----
#define AS_E 0            // softmax(a)  [16][136]
#define VS_E 2176         // softmax(v)
#define LS_E 4352         // softmax(l)
#define AV_E 6528         // a_v [16][136]
#define AL_E 8704         // a_l
#define VL_E 10880        // v_l
#define FUS_E 13056       // fusion [16][392]  (uni|bim|tri)
#define GH_E 19328        // overlay: G0..2 [16][128] + H3 [16][72]x3 / H6 / ll scratch
#define SCR_B 57856       // per-row scalars: [16][16] f32
#define SM_BYTES 58880

__device__ __forceinline__ float ex2(float x){ return __builtin_amdgcn_exp2f(x); }
__device__ __forceinline__ float rcpf_(float x){ return __builtin_amdgcn_rcpf(x); }
__device__ __forceinline__ float ftanh(float x){ return 1.0f - 2.0f*rcpf_(ex2(x*(2.0f*LOG2E)) + 1.0f); }
__device__ __forceinline__ u16 f2b(float x){ u32 u = __float_as_uint(x); return (u16)((u + 0x7FFFu + ((u>>16)&1u))>>16); }
__device__ __forceinline__ float b2f(u16 b){ return __uint_as_float(((u32)b)<<16); }
__device__ __forceinline__ float rsum16(float v){
  v += __shfl_xor(v,1); v += __shfl_xor(v,2); v += __shfl_xor(v,4); v += __shfl_xor(v,8); return v;
}
__device__ __forceinline__ float rmax16(float v){
  v = fmaxf(v,__shfl_xor(v,1)); v = fmaxf(v,__shfl_xor(v,2));
  v = fmaxf(v,__shfl_xor(v,4)); v = fmaxf(v,__shfl_xor(v,8)); return v;
}
__device__ __forceinline__ void st4b(u16* p, float x0,float x1,float x2,float x3){
  u32 lo = (u32)f2b(x0) | ((u32)f2b(x1)<<16);
  u32 hi = (u32)f2b(x2) | ((u32)f2b(x3)<<16);
  *(uint2*)p = make_uint2(lo,hi);
}

// ---- prep: transpose all weight matrices to bf16 [n][k] blobs in ws ----
// layout (u16 elems): gf_w1t@0 (64x256) | gf_w2t@16384 (128x64) | gf2_w1t@24576 |
//                     gf2_w2t@40960 | ll_w1t@49152 (64x384) | ll_w2t@73728 (64x64) | ll_w3t@77824 (128x64)
__global__ void prep_weights(const float* __restrict__ gf_w1, const float* __restrict__ gf_w2,
                             const float* __restrict__ gf2_w1, const float* __restrict__ gf2_w2,
                             const float* __restrict__ ll_w1, const float* __restrict__ ll_w2,
                             const float* __restrict__ ll_w3, u16* __restrict__ blob)
{
  u32 i = blockIdx.x*256u + threadIdx.x;
  if (i >= 86016u) return;
  u32 off, K, N; const float* src;
  if      (i < 16384u){ off=0u;     K=256u; N=64u;  src=gf_w1; }
  else if (i < 24576u){ off=16384u; K=64u;  N=128u; src=gf_w2; }
  else if (i < 40960u){ off=24576u; K=256u; N=64u;  src=gf2_w1; }
  else if (i < 49152u){ off=40960u; K=64u;  N=128u; src=gf2_w2; }
  else if (i < 73728u){ off=49152u; K=384u; N=64u;  src=ll_w1; }
  else if (i < 77824u){ off=73728u; K=64u;  N=64u;  src=ll_w2; }
  else               { off=77824u; K=64u;  N=128u; src=ll_w3; }
  u32 li = i - off, n = li / K, k = li - n*K;
  blob[i] = f2b(src[k*N + n]);   // wt[n][k] = w[k][n]
}

__global__ __launch_bounds__(256,2) void fused_graph(
    const float* __restrict__ Lg, const float* __restrict__ Ag, const float* __restrict__ Vg,
    const float* __restrict__ att_w, const float* __restrict__ att_b,
    const float* __restrict__ gf_b1, const float* __restrict__ gf_b2,
    const float* __restrict__ gf2_b1, const float* __restrict__ gf2_b2,
    const float* __restrict__ ll_b1, const float* __restrict__ ll_b2, const float* __restrict__ ll_b3,
    const u16* __restrict__ wb, float* __restrict__ out)
{
  __shared__ alignas(16) char sm[SM_BYTES];
  u16* smu = (u16*)sm;
  float* scr = (float*)(sm + SCR_B);

  const int tid = threadIdx.x;
  const int lane = tid & 63;
  const int w = tid >> 6;        // wave 0..3
  const int m = lane & 15;       // MFMA row(A)/col(B)/col(C)
  const int q = lane >> 4;       // quad: k-group (A/B), row-group (C)
  const int er = tid >> 4;       // elementwise row 0..15
  const int ep = tid & 15;       // elementwise lane-in-row
  const int row0 = blockIdx.x << 4;

  // ================= P0: attention scalars, unimodal, softmaxes, dots =================
  const int gb = (row0 + er)*128 + ep*4;
  facc A0 = *(const facc*)(Ag+gb), A1 = *(const facc*)(Ag+gb+64);
  facc V0 = *(const facc*)(Vg+gb), V1 = *(const facc*)(Vg+gb+64);
  facc L0 = *(const facc*)(Lg+gb), L1 = *(const facc*)(Lg+gb+64);
  facc W0 = *(const facc*)(att_w+ep*4), W1 = *(const facc*)(att_w+ep*4+64);
  float ab = att_b[0];
  float pa=0.f,pv=0.f,pl=0.f;
  #pragma unroll
  for (int i=0;i<4;i++){ pa += A0[i]*W0[i]+A1[i]*W1[i]; pv += V0[i]*W0[i]+V1[i]*W1[i]; pl += L0[i]*W0[i]+L1[i]*W1[i]; }
  float sa = ftanh(rsum16(pa)+ab), sv = ftanh(rsum16(pv)+ab), sl = ftanh(rsum16(pl)+ab);
  { // unimodal -> fusion cols 0..127
    u16* fu = smu + FUS_E + er*392 + ep*4;
    const float th = 1.0f/3.0f;
    st4b(fu,    (sa*A0[0]+sv*V0[0]+sl*L0[0])*th, (sa*A0[1]+sv*V0[1]+sl*L0[1])*th,
                (sa*A0[2]+sv*V0[2]+sl*L0[2])*th, (sa*A0[3]+sv*V0[3]+sl*L0[3])*th);
    st4b(fu+64, (sa*A1[0]+sv*V1[0]+sl*L1[0])*th, (sa*A1[1]+sv*V1[1]+sl*L1[1])*th,
                (sa*A1[2]+sv*V1[2]+sl*L1[2])*th, (sa*A1[3]+sv*V1[3]+sl*L1[3])*th);
  }
  // softmaxes (in place, f32 kept in regs; bf16 copies to LDS)
  #define SMAX(X0,X1,OFFE) { \
    float mx=-3.0e38f; \
    _Pragma("unroll") for (int i=0;i<4;i++){ mx=fmaxf(mx,fmaxf(X0[i],X1[i])); } \
    mx = rmax16(mx); float s_=0.f; \
    _Pragma("unroll") for (int i=0;i<4;i++){ X0[i]=ex2((X0[i]-mx)*LOG2E); X1[i]=ex2((X1[i]-mx)*LOG2E); s_+=X0[i]+X1[i]; } \
    s_ = rsum16(s_); float rs_ = rcpf_(s_); \
    _Pragma("unroll") for (int i=0;i<4;i++){ X0[i]*=rs_; X1[i]*=rs_; } \
    u16* dp_ = smu + (OFFE) + er*136 + ep*4; \
    st4b(dp_, X0[0],X0[1],X0[2],X0[3]); st4b(dp_+64, X1[0],X1[1],X1[2],X1[3]); }
  SMAX(A0,A1,AS_E)
  SMAX(V0,V1,VS_E)
  SMAX(L0,L1,LS_E)
  float dav=0.f,dal=0.f,dvl=0.f;
  #pragma unroll
  for (int i=0;i<4;i++){ dav += A0[i]*V0[i]+A1[i]*V1[i]; dal += A0[i]*L0[i]+A1[i]*L1[i]; dvl += V0[i]*L0[i]+V1[i]*L1[i]; }
  dav = rsum16(dav); dal = rsum16(dal); dvl = rsum16(dvl);
  float sav = (sa+sv)*rcpf_(dav+0.5f);
  float sal = (sa+sl)*rcpf_(dal+0.5f);
  float svl = (sl+sv)*rcpf_(dvl+0.5f);
  if (ep==0){ // normalize weights for bimodal
    float mx = fmaxf(sav,fmaxf(sal,svl));
    float e0 = ex2((sav-mx)*LOG2E), e1 = ex2((sal-mx)*LOG2E), e2 = ex2((svl-mx)*LOG2E);
    float rs = rcpf_(e0+e1+e2);
    scr[er*16+0]=e0*rs; scr[er*16+1]=e1*rs; scr[er*16+2]=e2*rs;
  }
  __syncthreads();

  // ================= P1: gf on 3 pairs =================
  const u16* g1t = wb;            // [64][256]
  const u16* g2t = wb + 16384;    // [128][64]
  bfrag B1[8];
  #pragma unroll
  for (int s=0;s<8;s++) B1[s] = *(const bfrag*)(g1t + (w*16+m)*256 + s*32 + q*8);
  bfrag B2[2][2];
  #pragma unroll
  for (int t=0;t<2;t++){
    #pragma unroll
    for (int s=0;s<2;s++) B2[t][s] = *(const bfrag*)(g2t + ((w+4*t)*16+m)*64 + s*32 + q*8);
  }
  facc acc0={0,0,0,0}, acc1={0,0,0,0}, acc2={0,0,0,0};
  #pragma unroll
  for (int s=0;s<8;s++){
    int k = s*32 + q*8, ko = k & 127; bool hi = (k >= 128);
    const u16* p0 = smu + (hi? VS_E:AS_E) + m*136 + ko;  // (a',v')
    const u16* p1 = smu + (hi? LS_E:AS_E) + m*136 + ko;  // (a',l')
    const u16* p2 = smu + (hi? LS_E:VS_E) + m*136 + ko;  // (v',l')
    acc0 = MFMA(*(const bfrag*)p0, B1[s], acc0);
    acc1 = MFMA(*(const bfrag*)p1, B1[s], acc1);
    acc2 = MFMA(*(const bfrag*)p2, B1[s], acc2);
  }
  { // leaky_relu -> H3 (elems GH_E+6144 = 25472)
    float b1v = gf_b1[w*16+m];
    #pragma unroll
    for (int r=0;r<4;r++){
      int rr = q*4+r;
      float h0 = acc0[r]+b1v; h0 = fmaxf(h0, 0.2f*h0);
      float h1 = acc1[r]+b1v; h1 = fmaxf(h1, 0.2f*h1);
      float h2 = acc2[r]+b1v; h2 = fmaxf(h2, 0.2f*h2);
      smu[25472 + 0*1152 + rr*72 + w*16+m] = f2b(h0);
      smu[25472 + 1*1152 + rr*72 + w*16+m] = f2b(h1);
      smu[25472 + 2*1152 + rr*72 + w*16+m] = f2b(h2);
    }
  }
  __syncthreads();
  facc c2[3][2] = {{{0,0,0,0},{0,0,0,0}},{{0,0,0,0},{0,0,0,0}},{{0,0,0,0},{0,0,0,0}}};
  #pragma unroll
  for (int s=0;s<2;s++){
    int k = s*32 + q*8;
    #pragma unroll
    for (int p3=0;p3<3;p3++){
      bfrag Af = *(const bfrag*)(smu + 25472 + p3*1152 + m*72 + k);
      c2[p3][0] = MFMA(Af, B2[0][s], c2[p3][0]);
      c2[p3][1] = MFMA(Af, B2[1][s], c2[p3][1]);
    }
  }
  { // G = tanh(..), a_v/a_l/v_l = tanh(n*g), bim accumulate in regs
    float b2v0 = gf_b2[w*16+m], b2v1 = gf_b2[(w+4)*16+m];
    float bim[2][4] = {{0,0,0,0},{0,0,0,0}};
    float nv[4][3];
    #pragma unroll
    for (int r=0;r<4;r++){ int rr=q*4+r; nv[r][0]=scr[rr*16+0]; nv[r][1]=scr[rr*16+1]; nv[r][2]=scr[rr*16+2]; }
    #pragma unroll
    for (int p3=0;p3<3;p3++){
      #pragma unroll
      for (int t=0;t<2;t++){
        float bb = t? b2v1 : b2v0;
        int cc = (w+4*t)*16+m;
        #pragma unroll
        for (int r=0;r<4;r++){
          int rr=q*4+r;
          float g = ftanh(c2[p3][t][r] + bb);
          smu[GH_E + p3*2048 + rr*128 + cc] = f2b(g);
          float tt = ftanh(nv[r][p3]*g);
          smu[AV_E + p3*2176 + rr*136 + cc] = f2b(tt);
          bim[t][r] += tt;
        }
      }
    }
    #pragma unroll
    for (int t=0;t<2;t++){
      #pragma unroll
      for (int r=0;r<4;r++)
        smu[FUS_E + (q*4+r)*392 + 128 + (w+4*t)*16+m] = f2b(bim[t][r]);
    }
  }
  __syncthreads();

  // ================= P2: softmax stats of G, 6 dots, n2 =================
  float E0[8], E1[8], E2[8];
  #define GSTAT(EA, G3) { \
    const u16* gp_ = smu + GH_E + (G3)*2048 + er*128 + ep*4; \
    float x_[8]; \
    _Pragma("unroll") for (int i=0;i<4;i++){ x_[i]=b2f(gp_[i]); x_[4+i]=b2f(gp_[64+i]); } \
    float mx_=-3.0e38f; \
    _Pragma("unroll") for (int j=0;j<8;j++) mx_=fmaxf(mx_,x_[j]); \
    mx_ = rmax16(mx_); float s_=0.f; \
    _Pragma("unroll") for (int j=0;j<8;j++){ x_[j]=ex2((x_[j]-mx_)*LOG2E); s_+=x_[j]; } \
    s_ = rsum16(s_); float rs_=rcpf_(s_); \
    _Pragma("unroll") for (int j=0;j<8;j++) EA[j]=x_[j]*rs_; }
  GSTAT(E0,0)
  GSTAT(E1,1)
  GSTAT(E2,2)
  float d01=0.f,d02=0.f,d12=0.f,d0l=0.f,d1v=0.f,d2a=0.f;
  #pragma unroll
  for (int i=0;i<4;i++){
    d01 += E0[i]*E1[i] + E0[4+i]*E1[4+i];
    d02 += E0[i]*E2[i] + E0[4+i]*E2[4+i];
    d12 += E1[i]*E2[i] + E1[4+i]*E2[4+i];
    d0l += E0[i]*L0[i] + E0[4+i]*L1[i];
    d1v += E1[i]*V0[i] + E1[4+i]*V1[i];
    d2a += E2[i]*A0[i] + E2[4+i]*A1[i];
  }
  d01=rsum16(d01); d02=rsum16(d02); d12=rsum16(d12);
  d0l=rsum16(d0l); d1v=rsum16(d1v); d2a=rsum16(d2a);
  if (ep==0){
    float x0 = (sav+svl)*rcpf_(d02+0.5f);  // savvl
    float x1 = (sav+sal)*rcpf_(d01+0.5f);  // saavl
    float x2 = (sal+svl)*rcpf_(d12+0.5f);  // savll
    float x3 = (sav+sl )*rcpf_(d0l+0.5f);  // savl
    float x4 = (sal+sv )*rcpf_(d1v+0.5f);  // salv
    float x5 = (sa +svl)*rcpf_(d2a+0.5f);  // svla
    float mx = fmaxf(fmaxf(fmaxf(x0,x1),fmaxf(x2,x3)),fmaxf(x4,x5));
    float e0=ex2((x0-mx)*LOG2E), e1=ex2((x1-mx)*LOG2E), e2=ex2((x2-mx)*LOG2E);
    float e3=ex2((x3-mx)*LOG2E), e4=ex2((x4-mx)*LOG2E), e5=ex2((x5-mx)*LOG2E);
    float rs = rcpf_(e0+e1+e2+e3+e4+e5);
    scr[er*16+ 9]=e0*rs; scr[er*16+10]=e1*rs; scr[er*16+11]=e2*rs;
    scr[er*16+12]=e3*rs; scr[er*16+13]=e4*rs; scr[er*16+14]=e5*rs;
  }
  __syncthreads();

  // ================= P3: gf2 on 6 pairs, trimodal =================
  const u16* h1t = wb + 24576;
  const u16* h2t = wb + 40960;
  bfrag C1[8];
  #pragma unroll
  for (int s=0;s<8;s++) C1[s] = *(const bfrag*)(h1t + (w*16+m)*256 + s*32 + q*8);
  bfrag C2[2][2];
  #pragma unroll
  for (int t=0;t<2;t++){
    #pragma unroll
    for (int s=0;s<2;s++) C2[t][s] = *(const bfrag*)(h2t + ((w+4*t)*16+m)*64 + s*32 + q*8);
  }
  const int S0[6] = {AV_E, AV_E, VL_E, AV_E, AL_E, VL_E};
  const int S1[6] = {VL_E, AL_E, AL_E, LS_E, VS_E, AS_E};
  facc cc1[6];
  #pragma unroll
  for (int pr=0;pr<6;pr++){ facc z = {0,0,0,0}; cc1[pr] = z; }
  #pragma unroll
  for (int s=0;s<8;s++){
    int k = s*32+q*8, ko = k&127; bool hi = (k>=128);
    #pragma unroll
    for (int pr=0;pr<6;pr++){
      const u16* sp = smu + (hi? S1[pr]:S0[pr]) + m*136 + ko;
      cc1[pr] = MFMA(*(const bfrag*)sp, C1[s], cc1[pr]);
    }
  }
  {
    float b1v = gf2_b1[w*16+m];
    #pragma unroll
    for (int pr=0;pr<6;pr++){
      #pragma unroll
      for (int r=0;r<4;r++){
        float h = cc1[pr][r]+b1v; h = fmaxf(h,0.2f*h);
        smu[GH_E + pr*1152 + (q*4+r)*72 + w*16+m] = f2b(h);  // H6 (overwrites dead G)
      }
    }
  }
  __syncthreads();
  facc cc2[6][2];
  #pragma unroll
  for (int pr=0;pr<6;pr++){ facc z = {0,0,0,0}; cc2[pr][0]=z; cc2[pr][1]=z; }
  #pragma unroll
  for (int s=0;s<2;s++){
    int k=s*32+q*8;
    #pragma unroll
    for (int pr=0;pr<6;pr++){
      bfrag Af = *(const bfrag*)(smu + GH_E + pr*1152 + m*72 + k);
      cc2[pr][0] = MFMA(Af, C2[0][s], cc2[pr][0]);
      cc2[pr][1] = MFMA(Af, C2[1][s], cc2[pr][1]);
    }
  }
  {
    float b2v0 = gf2_b2[w*16+m], b2v1 = gf2_b2[(w+4)*16+m];
    float tri[2][4] = {{0,0,0,0},{0,0,0,0}};
    float n2v[4][6];
    #pragma unroll
    for (int r=0;r<4;r++){
      #pragma unroll
      for (int j=0;j<6;j++) n2v[r][j] = scr[(q*4+r)*16+9+j];
    }
    #pragma unroll
    for (int pr=0;pr<6;pr++){
      #pragma unroll
      for (int t=0;t<2;t++){
        float bb = t? b2v1 : b2v0;
        #pragma unroll
        for (int r=0;r<4;r++){
          float g = ftanh(cc2[pr][t][r] + bb);
          tri[t][r] += ftanh(n2v[r][pr]*g);
        }
      }
    }
    #pragma unroll
    for (int t=0;t<2;t++){
      #pragma unroll
      for (int r=0;r<4;r++)
        smu[FUS_E + (q*4+r)*392 + 256 + (w+4*t)*16+m] = f2b(tri[t][r]);
    }
  }
  __syncthreads();

  // ================= P4: final head 384->64->64->128 =================
  const u16* lw1 = wb + 49152;
  const u16* lw2 = wb + 73728;
  const u16* lw3 = wb + 77824;
  {
    facc c = {0,0,0,0};
    #pragma unroll
    for (int s=0;s<12;s++){
      bfrag Bf = *(const bfrag*)(lw1 + (w*16+m)*384 + s*32 + q*8);
      bfrag Af = *(const bfrag*)(smu + FUS_E + m*392 + s*32 + q*8);
      c = MFMA(Af, Bf, c);
    }
    float b = ll_b1[w*16+m];
    #pragma unroll
    for (int r=0;r<4;r++) smu[GH_E + (q*4+r)*72 + w*16+m] = f2b(ftanh(c[r]+b));
  }
  __syncthreads();
  {
    facc c = {0,0,0,0};
    #pragma unroll
    for (int s=0;s<2;s++){
      bfrag Bf = *(const bfrag*)(lw2 + (w*16+m)*64 + s*32 + q*8);
      bfrag Af = *(const bfrag*)(smu + GH_E + m*72 + s*32 + q*8);
      c = MFMA(Af, Bf, c);
    }
    float b = ll_b2[w*16+m];
    #pragma unroll
    for (int r=0;r<4;r++) smu[GH_E + 1152 + (q*4+r)*72 + w*16+m] = f2b(ftanh(c[r]+b));
  }
  __syncthreads();
  {
    facc c0={0,0,0,0}, c1={0,0,0,0};
    #pragma unroll
    for (int s=0;s<2;s++){
      bfrag Af  = *(const bfrag*)(smu + GH_E + 1152 + m*72 + s*32 + q*8);
      bfrag Bf0 = *(const bfrag*)(lw3 + (w*16+m)*64 + s*32 + q*8);
      bfrag Bf1 = *(const bfrag*)(lw3 + ((w+4)*16+m)*64 + s*32 + q*8);
      c0 = MFMA(Af, Bf0, c0);
      c1 = MFMA(Af, Bf1, c1);
    }
    float b0 = ll_b3[w*16+m], b1 = ll_b3[(w+4)*16+m];
    #pragma unroll
    for (int r=0;r<4;r++){
      out[(row0+q*4+r)*128 + w*16+m]        = ftanh(c0[r]+b0);
      out[(row0+q*4+r)*128 + (w+4)*16+m]    = ftanh(c1[r]+b1);
    }
  }
}

extern "C" void kernel_launch(void* const* d_in, const int* in_sizes, int n_in,
                              void* d_out, int out_size, void* d_ws, size_t ws_size,
                              hipStream_t stream)
{
  const float* l      = (const float*)d_in[0];
  const float* a      = (const float*)d_in[1];
  const float* v      = (const float*)d_in[2];
  const float* att_w  = (const float*)d_in[3];
  const float* att_b  = (const float*)d_in[4];
  const float* gf_w1  = (const float*)d_in[5];
  const float* gf_b1  = (const float*)d_in[6];
  const float* gf_w2  = (const float*)d_in[7];
  const float* gf_b2  = (const float*)d_in[8];
  const float* gf2_w1 = (const float*)d_in[9];
  const float* gf2_b1 = (const float*)d_in[10];
  const float* gf2_w2 = (const float*)d_in[11];
  const float* gf2_b2 = (const float*)d_in[12];
  const float* ll_w1  = (const float*)d_in[13];
  const float* ll_b1  = (const float*)d_in[14];
  const float* ll_w2  = (const float*)d_in[15];
  const float* ll_b2  = (const float*)d_in[16];
  const float* ll_w3  = (const float*)d_in[17];
  const float* ll_b3  = (const float*)d_in[18];
  u16* blob = (u16*)d_ws;

  prep_weights<<<336, 256, 0, stream>>>(gf_w1, gf_w2, gf2_w1, gf2_w2, ll_w1, ll_w2, ll_w3, blob);
  fused_graph<<<4096, 256, 0, stream>>>(l, a, v, att_w, att_b,
                                        gf_b1, gf_b2, gf2_b1, gf2_b2,
                                        ll_b1, ll_b2, ll_b3, blob, (float*)d_out);
}

// Round 2
// 255.475 us; speedup vs baseline: 1.0863x; 1.0863x over previous
//
#include <hip/hip_runtime.h>

typedef short bfrag __attribute__((ext_vector_type(8)));   // 8 x bf16 (4 VGPRs)
typedef float facc  __attribute__((ext_vector_type(4)));   // MFMA accumulator
typedef unsigned short u16;
typedef unsigned int   u32;

#define LOG2E 1.4426950408889634f
#define MFMA(A,B,C) __builtin_amdgcn_mfma_f32_16x16x32_bf16((A),(B),(C),0,0,0)

// ---- LDS element offsets (u16 units) ----
#define AS_E 0            // softmax(a)  [16][136]
#define VS_E 2176         // softmax(v)
#define LS_E 4352         // softmax(l)
#define AV_E 6528         // a_v [16][136]
#define AL_E 8704         // a_l
#define VL_E 10880        // v_l
#define FUS_E 13056       // fusion [16][392]  (uni|bim|tri)
// HH region (6912 elems): time-multiplexed H3 (3x[16][72]) -> G (3x[16][128])
//                         -> H6 (6x[16][72]) -> ll scratch (2x[16][72])
#define HH_E 19328
#define SCR_B 52480       // per-row scalars: [16][16] f32
#define SM_BYTES 53504    // 53504*3 = 160512 <= 163840 -> 3 blocks/CU

__device__ __forceinline__ float ex2(float x){ return __builtin_amdgcn_exp2f(x); }
__device__ __forceinline__ float rcpf_(float x){ return __builtin_amdgcn_rcpf(x); }
__device__ __forceinline__ float ftanh(float x){ return 1.0f - 2.0f*rcpf_(ex2(x*(2.0f*LOG2E)) + 1.0f); }
// round-to-nearest (ties up) bf16: +0.5ulp bias only on exact ties — negligible
__device__ __forceinline__ u16 f2b(float x){ return (u16)((__float_as_uint(x) + 0x8000u)>>16); }
__device__ __forceinline__ float b2f(u16 b){ return __uint_as_float(((u32)b)<<16); }
// pack two f32 -> two bf16 in one u32 via v_perm_b32 (3 VALU ops)
__device__ __forceinline__ u32 pk2(float x0, float x1){
  return __builtin_amdgcn_perm(__float_as_uint(x1)+0x8000u, __float_as_uint(x0)+0x8000u, 0x07060302u);
}
__device__ __forceinline__ float rsum16(float v){
  v += __shfl_xor(v,1); v += __shfl_xor(v,2); v += __shfl_xor(v,4); v += __shfl_xor(v,8); return v;
}
__device__ __forceinline__ float rmax16(float v){
  v = fmaxf(v,__shfl_xor(v,1)); v = fmaxf(v,__shfl_xor(v,2));
  v = fmaxf(v,__shfl_xor(v,4)); v = fmaxf(v,__shfl_xor(v,8)); return v;
}
__device__ __forceinline__ void st4b(u16* p, float x0,float x1,float x2,float x3){
  *(uint2*)p = make_uint2(pk2(x0,x1), pk2(x2,x3));
}

// ---- prep: transpose all weight matrices to bf16 [n][k] blobs in ws ----
// layout (u16 elems): gf_w1t@0 (64x256) | gf_w2t@16384 (128x64) | gf2_w1t@24576 |
//                     gf2_w2t@40960 | ll_w1t@49152 (64x384) | ll_w2t@73728 (64x64) | ll_w3t@77824 (128x64)
__global__ void prep_weights(const float* __restrict__ gf_w1, const float* __restrict__ gf_w2,
                             const float* __restrict__ gf2_w1, const float* __restrict__ gf2_w2,
                             const float* __restrict__ ll_w1, const float* __restrict__ ll_w2,
                             const float* __restrict__ ll_w3, u16* __restrict__ blob)
{
  u32 i = blockIdx.x*256u + threadIdx.x;
  if (i >= 86016u) return;
  u32 off, K, N; const float* src;
  if      (i < 16384u){ off=0u;     K=256u; N=64u;  src=gf_w1; }
  else if (i < 24576u){ off=16384u; K=64u;  N=128u; src=gf_w2; }
  else if (i < 40960u){ off=24576u; K=256u; N=64u;  src=gf2_w1; }
  else if (i < 49152u){ off=40960u; K=64u;  N=128u; src=gf2_w2; }
  else if (i < 73728u){ off=49152u; K=384u; N=64u;  src=ll_w1; }
  else if (i < 77824u){ off=73728u; K=64u;  N=64u;  src=ll_w2; }
  else               { off=77824u; K=64u;  N=128u; src=ll_w3; }
  u32 li = i - off, n = li / K, k = li - n*K;
  blob[i] = f2b(src[k*N + n]);   // wt[n][k] = w[k][n]
}

__global__ __launch_bounds__(256,3) void fused_graph(
    const float* __restrict__ Lg, const float* __restrict__ Ag, const float* __restrict__ Vg,
    const float* __restrict__ att_w, const float* __restrict__ att_b,
    const float* __restrict__ gf_b1, const float* __restrict__ gf_b2,
    const float* __restrict__ gf2_b1, const float* __restrict__ gf2_b2,
    const float* __restrict__ ll_b1, const float* __restrict__ ll_b2, const float* __restrict__ ll_b3,
    const u16* __restrict__ wb, float* __restrict__ out)
{
  __shared__ alignas(16) char sm[SM_BYTES];
  u16* smu = (u16*)sm;
  float* scr = (float*)(sm + SCR_B);

  const int tid = threadIdx.x;
  const int lane = tid & 63;
  const int w = tid >> 6;        // wave 0..3
  const int m = lane & 15;       // MFMA row(A)/col(B)/col(C)
  const int q = lane >> 4;       // quad: k-group (A/B), row-group (C)
  const int er = tid >> 4;       // elementwise row 0..15
  const int ep = tid & 15;       // elementwise lane-in-row
  const int row0 = blockIdx.x << 4;

  // ================= P0: attention scalars, unimodal, softmaxes, dots =================
  const int gb = (row0 + er)*128 + ep*4;
  facc A0 = *(const facc*)(Ag+gb), A1 = *(const facc*)(Ag+gb+64);
  facc V0 = *(const facc*)(Vg+gb), V1 = *(const facc*)(Vg+gb+64);
  facc L0 = *(const facc*)(Lg+gb), L1 = *(const facc*)(Lg+gb+64);
  facc W0 = *(const facc*)(att_w+ep*4), W1 = *(const facc*)(att_w+ep*4+64);
  float ab = att_b[0];
  float pa=0.f,pv=0.f,pl=0.f;
  #pragma unroll
  for (int i=0;i<4;i++){ pa += A0[i]*W0[i]+A1[i]*W1[i]; pv += V0[i]*W0[i]+V1[i]*W1[i]; pl += L0[i]*W0[i]+L1[i]*W1[i]; }
  float sa = ftanh(rsum16(pa)+ab), sv = ftanh(rsum16(pv)+ab), sl = ftanh(rsum16(pl)+ab);
  { // unimodal -> fusion cols 0..127
    u16* fu = smu + FUS_E + er*392 + ep*4;
    const float th = 1.0f/3.0f;
    st4b(fu,    (sa*A0[0]+sv*V0[0]+sl*L0[0])*th, (sa*A0[1]+sv*V0[1]+sl*L0[1])*th,
                (sa*A0[2]+sv*V0[2]+sl*L0[2])*th, (sa*A0[3]+sv*V0[3]+sl*L0[3])*th);
    st4b(fu+64, (sa*A1[0]+sv*V1[0]+sl*L1[0])*th, (sa*A1[1]+sv*V1[1]+sl*L1[1])*th,
                (sa*A1[2]+sv*V1[2]+sl*L1[2])*th, (sa*A1[3]+sv*V1[3]+sl*L1[3])*th);
  }
  // softmaxes (in place, f32 kept in regs; bf16 copies to LDS)
  #define SMAX(X0,X1,OFFE) { \
    float mx=-3.0e38f; \
    _Pragma("unroll") for (int i=0;i<4;i++){ mx=fmaxf(mx,fmaxf(X0[i],X1[i])); } \
    mx = rmax16(mx); float s_=0.f; \
    _Pragma("unroll") for (int i=0;i<4;i++){ X0[i]=ex2((X0[i]-mx)*LOG2E); X1[i]=ex2((X1[i]-mx)*LOG2E); s_+=X0[i]+X1[i]; } \
    s_ = rsum16(s_); float rs_ = rcpf_(s_); \
    _Pragma("unroll") for (int i=0;i<4;i++){ X0[i]*=rs_; X1[i]*=rs_; } \
    u16* dp_ = smu + (OFFE) + er*136 + ep*4; \
    st4b(dp_, X0[0],X0[1],X0[2],X0[3]); st4b(dp_+64, X1[0],X1[1],X1[2],X1[3]); }
  SMAX(A0,A1,AS_E)
  SMAX(V0,V1,VS_E)
  SMAX(L0,L1,LS_E)
  float dav=0.f,dal=0.f,dvl=0.f;
  #pragma unroll
  for (int i=0;i<4;i++){ dav += A0[i]*V0[i]+A1[i]*V1[i]; dal += A0[i]*L0[i]+A1[i]*L1[i]; dvl += V0[i]*L0[i]+V1[i]*L1[i]; }
  dav = rsum16(dav); dal = rsum16(dal); dvl = rsum16(dvl);
  float sav = (sa+sv)*rcpf_(dav+0.5f);
  float sal = (sa+sl)*rcpf_(dal+0.5f);
  float svl = (sl+sv)*rcpf_(dvl+0.5f);
  if (ep==0){ // normalize weights for bimodal
    float mx = fmaxf(sav,fmaxf(sal,svl));
    float e0 = ex2((sav-mx)*LOG2E), e1 = ex2((sal-mx)*LOG2E), e2 = ex2((svl-mx)*LOG2E);
    float rs = rcpf_(e0+e1+e2);
    scr[er*16+0]=e0*rs; scr[er*16+1]=e1*rs; scr[er*16+2]=e2*rs;
  }
  __syncthreads();   // (1) softmaxes+scr ready

  // ================= P1: gf on 3 pairs =================
  const u16* g1t = wb;            // [64][256]
  const u16* g2t = wb + 16384;    // [128][64]
  bfrag B1[8];
  #pragma unroll
  for (int s=0;s<8;s++) B1[s] = *(const bfrag*)(g1t + (w*16+m)*256 + s*32 + q*8);
  bfrag B2[2][2];
  #pragma unroll
  for (int t=0;t<2;t++){
    #pragma unroll
    for (int s=0;s<2;s++) B2[t][s] = *(const bfrag*)(g2t + ((w+4*t)*16+m)*64 + s*32 + q*8);
  }
  facc acc0={0,0,0,0}, acc1={0,0,0,0}, acc2={0,0,0,0};
  #pragma unroll
  for (int s=0;s<8;s++){
    int k = s*32 + q*8, ko = k & 127; bool hi = (k >= 128);
    const u16* p0 = smu + (hi? VS_E:AS_E) + m*136 + ko;  // (a',v')
    const u16* p1 = smu + (hi? LS_E:AS_E) + m*136 + ko;  // (a',l')
    const u16* p2 = smu + (hi? LS_E:VS_E) + m*136 + ko;  // (v',l')
    acc0 = MFMA(*(const bfrag*)p0, B1[s], acc0);
    acc1 = MFMA(*(const bfrag*)p1, B1[s], acc1);
    acc2 = MFMA(*(const bfrag*)p2, B1[s], acc2);
  }
  { // leaky_relu -> H3 @ HH_E
    float b1v = gf_b1[w*16+m];
    #pragma unroll
    for (int r=0;r<4;r++){
      int rr = q*4+r;
      float h0 = acc0[r]+b1v; h0 = fmaxf(h0, 0.2f*h0);
      float h1 = acc1[r]+b1v; h1 = fmaxf(h1, 0.2f*h1);
      float h2 = acc2[r]+b1v; h2 = fmaxf(h2, 0.2f*h2);
      smu[HH_E + 0*1152 + rr*72 + w*16+m] = f2b(h0);
      smu[HH_E + 1*1152 + rr*72 + w*16+m] = f2b(h1);
      smu[HH_E + 2*1152 + rr*72 + w*16+m] = f2b(h2);
    }
  }
  __syncthreads();   // (2) H3 ready
  facc c2[3][2] = {{{0,0,0,0},{0,0,0,0}},{{0,0,0,0},{0,0,0,0}},{{0,0,0,0},{0,0,0,0}}};
  #pragma unroll
  for (int s=0;s<2;s++){
    int k = s*32 + q*8;
    #pragma unroll
    for (int p3=0;p3<3;p3++){
      bfrag Af = *(const bfrag*)(smu + HH_E + p3*1152 + m*72 + k);
      c2[p3][0] = MFMA(Af, B2[0][s], c2[p3][0]);
      c2[p3][1] = MFMA(Af, B2[1][s], c2[p3][1]);
    }
  }
  __syncthreads();   // (2b) H3 consumed — HH region free for G
  { // G = tanh(..) @ HH_E (overlays dead H3), a_v/a_l/v_l = tanh(n*g), bim in regs
    float b2v0 = gf_b2[w*16+m], b2v1 = gf_b2[(w+4)*16+m];
    float bim[2][4] = {{0,0,0,0},{0,0,0,0}};
    float nv[4][3];
    #pragma unroll
    for (int r=0;r<4;r++){ int rr=q*4+r; nv[r][0]=scr[rr*16+0]; nv[r][1]=scr[rr*16+1]; nv[r][2]=scr[rr*16+2]; }
    #pragma unroll
    for (int p3=0;p3<3;p3++){
      #pragma unroll
      for (int t=0;t<2;t++){
        float bb = t? b2v1 : b2v0;
        int cc = (w+4*t)*16+m;
        #pragma unroll
        for (int r=0;r<4;r++){
          int rr=q*4+r;
          float g = ftanh(c2[p3][t][r] + bb);
          smu[HH_E + p3*2048 + rr*128 + cc] = f2b(g);
          float tt = ftanh(nv[r][p3]*g);
          smu[AV_E + p3*2176 + rr*136 + cc] = f2b(tt);
          bim[t][r] += tt;
        }
      }
    }
    #pragma unroll
    for (int t=0;t<2;t++){
      #pragma unroll
      for (int r=0;r<4;r++)
        smu[FUS_E + (q*4+r)*392 + 128 + (w+4*t)*16+m] = f2b(bim[t][r]);
    }
  }
  __syncthreads();   // (3) G + AV/AL/VL + bim ready

  // ================= P2: softmax stats of G, 6 dots, n2 =================
  float E0[8], E1[8], E2[8];
  #define GSTAT(EA, G3) { \
    const u16* gp_ = smu + HH_E + (G3)*2048 + er*128 + ep*4; \
    float x_[8]; \
    _Pragma("unroll") for (int i=0;i<4;i++){ x_[i]=b2f(gp_[i]); x_[4+i]=b2f(gp_[64+i]); } \
    float mx_=-3.0e38f; \
    _Pragma("unroll") for (int j=0;j<8;j++) mx_=fmaxf(mx_,x_[j]); \
    mx_ = rmax16(mx_); float s_=0.f; \
    _Pragma("unroll") for (int j=0;j<8;j++){ x_[j]=ex2((x_[j]-mx_)*LOG2E); s_+=x_[j]; } \
    s_ = rsum16(s_); float rs_=rcpf_(s_); \
    _Pragma("unroll") for (int j=0;j<8;j++) EA[j]=x_[j]*rs_; }
  GSTAT(E0,0)
  GSTAT(E1,1)
  GSTAT(E2,2)
  float d01=0.f,d02=0.f,d12=0.f,d0l=0.f,d1v=0.f,d2a=0.f;
  #pragma unroll
  for (int i=0;i<4;i++){
    d01 += E0[i]*E1[i] + E0[4+i]*E1[4+i];
    d02 += E0[i]*E2[i] + E0[4+i]*E2[4+i];
    d12 += E1[i]*E2[i] + E1[4+i]*E2[4+i];
    d0l += E0[i]*L0[i] + E0[4+i]*L1[i];
    d1v += E1[i]*V0[i] + E1[4+i]*V1[i];
    d2a += E2[i]*A0[i] + E2[4+i]*A1[i];
  }
  d01=rsum16(d01); d02=rsum16(d02); d12=rsum16(d12);
  d0l=rsum16(d0l); d1v=rsum16(d1v); d2a=rsum16(d2a);
  if (ep==0){
    float x0 = (sav+svl)*rcpf_(d02+0.5f);  // savvl
    float x1 = (sav+sal)*rcpf_(d01+0.5f);  // saavl
    float x2 = (sal+svl)*rcpf_(d12+0.5f);  // savll
    float x3 = (sav+sl )*rcpf_(d0l+0.5f);  // savl
    float x4 = (sal+sv )*rcpf_(d1v+0.5f);  // salv
    float x5 = (sa +svl)*rcpf_(d2a+0.5f);  // svla
    float mx = fmaxf(fmaxf(fmaxf(x0,x1),fmaxf(x2,x3)),fmaxf(x4,x5));
    float e0=ex2((x0-mx)*LOG2E), e1=ex2((x1-mx)*LOG2E), e2=ex2((x2-mx)*LOG2E);
    float e3=ex2((x3-mx)*LOG2E), e4=ex2((x4-mx)*LOG2E), e5=ex2((x5-mx)*LOG2E);
    float rs = rcpf_(e0+e1+e2+e3+e4+e5);
    scr[er*16+ 9]=e0*rs; scr[er*16+10]=e1*rs; scr[er*16+11]=e2*rs;
    scr[er*16+12]=e3*rs; scr[er*16+13]=e4*rs; scr[er*16+14]=e5*rs;
  }
  __syncthreads();   // (4) G consumed (HH free for H6), n2 ready

  // ================= P3: gf2 on 6 pairs, trimodal =================
  const u16* h1t = wb + 24576;
  const u16* h2t = wb + 40960;
  bfrag C1[8];
  #pragma unroll
  for (int s=0;s<8;s++) C1[s] = *(const bfrag*)(h1t + (w*16+m)*256 + s*32 + q*8);
  bfrag C2[2][2];
  #pragma unroll
  for (int t=0;t<2;t++){
    #pragma unroll
    for (int s=0;s<2;s++) C2[t][s] = *(const bfrag*)(h2t + ((w+4*t)*16+m)*64 + s*32 + q*8);
  }
  const int S0[6] = {AV_E, AV_E, VL_E, AV_E, AL_E, VL_E};
  const int S1[6] = {VL_E, AL_E, AL_E, LS_E, VS_E, AS_E};
  facc cc1[6];
  #pragma unroll
  for (int pr=0;pr<6;pr++){ facc z = {0,0,0,0}; cc1[pr] = z; }
  #pragma unroll
  for (int s=0;s<8;s++){
    int k = s*32+q*8, ko = k&127; bool hi = (k>=128);
    #pragma unroll
    for (int pr=0;pr<6;pr++){
      const u16* sp = smu + (hi? S1[pr]:S0[pr]) + m*136 + ko;
      cc1[pr] = MFMA(*(const bfrag*)sp, C1[s], cc1[pr]);
    }
  }
  {
    float b1v = gf2_b1[w*16+m];
    #pragma unroll
    for (int pr=0;pr<6;pr++){
      #pragma unroll
      for (int r=0;r<4;r++){
        float h = cc1[pr][r]+b1v; h = fmaxf(h,0.2f*h);
        smu[HH_E + pr*1152 + (q*4+r)*72 + w*16+m] = f2b(h);  // H6 (overlays dead G)
      }
    }
  }
  __syncthreads();   // (5) H6 ready
  facc cc2[6][2];
  #pragma unroll
  for (int pr=0;pr<6;pr++){ facc z = {0,0,0,0}; cc2[pr][0]=z; cc2[pr][1]=z; }
  #pragma unroll
  for (int s=0;s<2;s++){
    int k=s*32+q*8;
    #pragma unroll
    for (int pr=0;pr<6;pr++){
      bfrag Af = *(const bfrag*)(smu + HH_E + pr*1152 + m*72 + k);
      cc2[pr][0] = MFMA(Af, C2[0][s], cc2[pr][0]);
      cc2[pr][1] = MFMA(Af, C2[1][s], cc2[pr][1]);
    }
  }
  {
    float b2v0 = gf2_b2[w*16+m], b2v1 = gf2_b2[(w+4)*16+m];
    float tri[2][4] = {{0,0,0,0},{0,0,0,0}};
    float n2v[4][6];
    #pragma unroll
    for (int r=0;r<4;r++){
      #pragma unroll
      for (int j=0;j<6;j++) n2v[r][j] = scr[(q*4+r)*16+9+j];
    }
    #pragma unroll
    for (int pr=0;pr<6;pr++){
      #pragma unroll
      for (int t=0;t<2;t++){
        float bb = t? b2v1 : b2v0;
        #pragma unroll
        for (int r=0;r<4;r++){
          float g = ftanh(cc2[pr][t][r] + bb);
          tri[t][r] += ftanh(n2v[r][pr]*g);
        }
      }
    }
    #pragma unroll
    for (int t=0;t<2;t++){
      #pragma unroll
      for (int r=0;r<4;r++)
        smu[FUS_E + (q*4+r)*392 + 256 + (w+4*t)*16+m] = f2b(tri[t][r]);
    }
  }
  __syncthreads();   // (6) fusion complete, H6 consumed (HH free for ll scratch)

  // ================= P4: final head 384->64->64->128 =================
  const u16* lw1 = wb + 49152;
  const u16* lw2 = wb + 73728;
  const u16* lw3 = wb + 77824;
  {
    facc c = {0,0,0,0};
    #pragma unroll
    for (int s=0;s<12;s++){
      bfrag Bf = *(const bfrag*)(lw1 + (w*16+m)*384 + s*32 + q*8);
      bfrag Af = *(const bfrag*)(smu + FUS_E + m*392 + s*32 + q*8);
      c = MFMA(Af, Bf, c);
    }
    float b = ll_b1[w*16+m];
    #pragma unroll
    for (int r=0;r<4;r++) smu[HH_E + (q*4+r)*72 + w*16+m] = f2b(ftanh(c[r]+b));
  }
  __syncthreads();   // (7)
  {
    facc c = {0,0,0,0};
    #pragma unroll
    for (int s=0;s<2;s++){
      bfrag Bf = *(const bfrag*)(lw2 + (w*16+m)*64 + s*32 + q*8);
      bfrag Af = *(const bfrag*)(smu + HH_E + m*72 + s*32 + q*8);
      c = MFMA(Af, Bf, c);
    }
    float b = ll_b2[w*16+m];
    #pragma unroll
    for (int r=0;r<4;r++) smu[HH_E + 1152 + (q*4+r)*72 + w*16+m] = f2b(ftanh(c[r]+b));
  }
  __syncthreads();   // (8)
  {
    facc c0={0,0,0,0}, c1={0,0,0,0};
    #pragma unroll
    for (int s=0;s<2;s++){
      bfrag Af  = *(const bfrag*)(smu + HH_E + 1152 + m*72 + s*32 + q*8);
      bfrag Bf0 = *(const bfrag*)(lw3 + (w*16+m)*64 + s*32 + q*8);
      bfrag Bf1 = *(const bfrag*)(lw3 + ((w+4)*16+m)*64 + s*32 + q*8);
      c0 = MFMA(Af, Bf0, c0);
      c1 = MFMA(Af, Bf1, c1);
    }
    float b0 = ll_b3[w*16+m], b1 = ll_b3[(w+4)*16+m];
    #pragma unroll
    for (int r=0;r<4;r++){
      out[(row0+q*4+r)*128 + w*16+m]        = ftanh(c0[r]+b0);
      out[(row0+q*4+r)*128 + (w+4)*16+m]    = ftanh(c1[r]+b1);
    }
  }
}

extern "C" void kernel_launch(void* const* d_in, const int* in_sizes, int n_in,
                              void* d_out, int out_size, void* d_ws, size_t ws_size,
                              hipStream_t stream)
{
  const float* l      = (const float*)d_in[0];
  const float* a      = (const float*)d_in[1];
  const float* v      = (const float*)d_in[2];
  const float* att_w  = (const float*)d_in[3];
  const float* att_b  = (const float*)d_in[4];
  const float* gf_w1  = (const float*)d_in[5];
  const float* gf_b1  = (const float*)d_in[6];
  const float* gf_w2  = (const float*)d_in[7];
  const float* gf_b2  = (const float*)d_in[8];
  const float* gf2_w1 = (const float*)d_in[9];
  const float* gf2_b1 = (const float*)d_in[10];
  const float* gf2_w2 = (const float*)d_in[11];
  const float* gf2_b2 = (const float*)d_in[12];
  const float* ll_w1  = (const float*)d_in[13];
  const float* ll_b1  = (const float*)d_in[14];
  const float* ll_w2  = (const float*)d_in[15];
  const float* ll_b2  = (const float*)d_in[16];
  const float* ll_w3  = (const float*)d_in[17];
  const float* ll_b3  = (const float*)d_in[18];
  u16* blob = (u16*)d_ws;

  prep_weights<<<336, 256, 0, stream>>>(gf_w1, gf_w2, gf2_w1, gf2_w2, ll_w1, ll_w2, ll_w3, blob);
  fused_graph<<<4096, 256, 0, stream>>>(l, a, v, att_w, att_b,
                                        gf_b1, gf_b2, gf2_b1, gf2_b2,
                                        ll_b1, ll_b2, ll_b3, blob, (float*)d_out);
}

// Round 3
// 249.503 us; speedup vs baseline: 1.1123x; 1.0239x over previous
//
#include <hip/hip_runtime.h>

typedef short bfrag __attribute__((ext_vector_type(8)));   // 8 x bf16 (4 VGPRs)
typedef float facc  __attribute__((ext_vector_type(4)));   // MFMA accumulator
typedef unsigned short u16;
typedef unsigned int   u32;

#define LOG2E 1.4426950408889634f
#define MFMA(A,B,C) __builtin_amdgcn_mfma_f32_16x16x32_bf16((A),(B),(C),0,0,0)

// ---- LDS element offsets (u16 units) ----
// AS/VS/LS: softmax(a/v/l) [16][136]; after P3-cc1 they die and are reused as
//           uni/bim/tri fusion segments for P4.
#define AS_E 0
#define VS_E 2176
#define LS_E 4352
#define AV_E 6528         // a_v [16][136]
#define AL_E 8704         // a_l
#define VL_E 10880        // v_l
// HH region (6912 elems): time-multiplexed H3 (3x[16][72]) -> G (3x[16][136])
//                         -> H6 (6x[16][72]) -> ll scratch (2x[16][72])
#define HH_E 13056
#define SCR_B 39936       // per-row scalars: [16][12] f32 (768 B)
#define SM_BYTES 40704    // +256 granularity -> 40960; 4 blocks/CU exactly

__device__ __forceinline__ float ex2(float x){ return __builtin_amdgcn_exp2f(x); }
__device__ __forceinline__ float rcpf_(float x){ return __builtin_amdgcn_rcpf(x); }
__device__ __forceinline__ float ftanh(float x){ return 1.0f - 2.0f*rcpf_(ex2(x*(2.0f*LOG2E)) + 1.0f); }
__device__ __forceinline__ u16 f2b(float x){ return (u16)((__float_as_uint(x) + 0x8000u)>>16); }
__device__ __forceinline__ float b2f(u16 b){ return __uint_as_float(((u32)b)<<16); }
__device__ __forceinline__ u32 pk2(float x0, float x1){
  return __builtin_amdgcn_perm(__float_as_uint(x1)+0x8000u, __float_as_uint(x0)+0x8000u, 0x07060302u);
}
// 16-lane reductions via DPP row_ror (VALU pipe, not LDS): rotation works for
// commutative reduce; every lane ends with the full 16-lane result.
template<int N>
__device__ __forceinline__ float ror16f(float v){
  return __int_as_float(__builtin_amdgcn_update_dpp(0, __float_as_int(v), 0x120|N, 0xF, 0xF, false));
}
__device__ __forceinline__ float rsum16(float v){
  v += ror16f<8>(v); v += ror16f<4>(v); v += ror16f<2>(v); v += ror16f<1>(v); return v;
}
__device__ __forceinline__ float rmax16(float v){
  v = fmaxf(v,ror16f<8>(v)); v = fmaxf(v,ror16f<4>(v));
  v = fmaxf(v,ror16f<2>(v)); v = fmaxf(v,ror16f<1>(v)); return v;
}
__device__ __forceinline__ void st4b(u16* p, float x0,float x1,float x2,float x3){
  *(uint2*)p = make_uint2(pk2(x0,x1), pk2(x2,x3));
}

// ---- prep: transpose all weight matrices to bf16 [n][k] blobs in ws ----
__global__ void prep_weights(const float* __restrict__ gf_w1, const float* __restrict__ gf_w2,
                             const float* __restrict__ gf2_w1, const float* __restrict__ gf2_w2,
                             const float* __restrict__ ll_w1, const float* __restrict__ ll_w2,
                             const float* __restrict__ ll_w3, u16* __restrict__ blob)
{
  u32 i = blockIdx.x*256u + threadIdx.x;
  if (i >= 86016u) return;
  u32 off, K, N; const float* src;
  if      (i < 16384u){ off=0u;     K=256u; N=64u;  src=gf_w1; }
  else if (i < 24576u){ off=16384u; K=64u;  N=128u; src=gf_w2; }
  else if (i < 40960u){ off=24576u; K=256u; N=64u;  src=gf2_w1; }
  else if (i < 49152u){ off=40960u; K=64u;  N=128u; src=gf2_w2; }
  else if (i < 73728u){ off=49152u; K=384u; N=64u;  src=ll_w1; }
  else if (i < 77824u){ off=73728u; K=64u;  N=64u;  src=ll_w2; }
  else               { off=77824u; K=64u;  N=128u; src=ll_w3; }
  u32 li = i - off, n = li / K, k = li - n*K;
  blob[i] = f2b(src[k*N + n]);   // wt[n][k] = w[k][n]
}

__global__ __launch_bounds__(256,4) void fused_graph(
    const float* __restrict__ Lg, const float* __restrict__ Ag, const float* __restrict__ Vg,
    const float* __restrict__ att_w, const float* __restrict__ att_b,
    const float* __restrict__ gf_b1, const float* __restrict__ gf_b2,
    const float* __restrict__ gf2_b1, const float* __restrict__ gf2_b2,
    const float* __restrict__ ll_b1, const float* __restrict__ ll_b2, const float* __restrict__ ll_b3,
    const u16* __restrict__ wb, float* __restrict__ out)
{
  __shared__ alignas(16) char sm[SM_BYTES];
  u16* smu = (u16*)sm;
  float* scr = (float*)(sm + SCR_B);

  const int tid = threadIdx.x;
  const int lane = tid & 63;
  const int w = tid >> 6;        // wave 0..3
  const int m = lane & 15;       // MFMA row(A)/col(B)/col(C)
  const int q = lane >> 4;       // quad
  const int er = tid >> 4;       // elementwise row 0..15
  const int ep = tid & 15;       // elementwise lane-in-row
  const int row0 = blockIdx.x << 4;

  // ================= P0: attention scalars, unimodal(->regs), softmaxes, dots =================
  const int gb = (row0 + er)*128 + ep*4;
  facc A0 = *(const facc*)(Ag+gb), A1 = *(const facc*)(Ag+gb+64);
  facc V0 = *(const facc*)(Vg+gb), V1 = *(const facc*)(Vg+gb+64);
  facc L0 = *(const facc*)(Lg+gb), L1 = *(const facc*)(Lg+gb+64);
  facc W0 = *(const facc*)(att_w+ep*4), W1 = *(const facc*)(att_w+ep*4+64);
  float ab = att_b[0];
  float pa=0.f,pv=0.f,pl=0.f;
  #pragma unroll
  for (int i=0;i<4;i++){ pa += A0[i]*W0[i]+A1[i]*W1[i]; pv += V0[i]*W0[i]+V1[i]*W1[i]; pl += L0[i]*W0[i]+L1[i]*W1[i]; }
  float sa = ftanh(rsum16(pa)+ab), sv = ftanh(rsum16(pv)+ab), sl = ftanh(rsum16(pl)+ab);
  // unimodal: pack to 4 u32 (bf16x2), store to LDS later (P3-ep) when AS frees up
  u32 uni_pk[4];
  {
    const float th = 1.0f/3.0f;
    uni_pk[0] = pk2((sa*A0[0]+sv*V0[0]+sl*L0[0])*th, (sa*A0[1]+sv*V0[1]+sl*L0[1])*th);
    uni_pk[1] = pk2((sa*A0[2]+sv*V0[2]+sl*L0[2])*th, (sa*A0[3]+sv*V0[3]+sl*L0[3])*th);
    uni_pk[2] = pk2((sa*A1[0]+sv*V1[0]+sl*L1[0])*th, (sa*A1[1]+sv*V1[1]+sl*L1[1])*th);
    uni_pk[3] = pk2((sa*A1[2]+sv*V1[2]+sl*L1[2])*th, (sa*A1[3]+sv*V1[3]+sl*L1[3])*th);
  }
  #define SMAX(X0,X1,OFFE) { \
    float mx=-3.0e38f; \
    _Pragma("unroll") for (int i=0;i<4;i++){ mx=fmaxf(mx,fmaxf(X0[i],X1[i])); } \
    mx = rmax16(mx); float s_=0.f; \
    _Pragma("unroll") for (int i=0;i<4;i++){ X0[i]=ex2((X0[i]-mx)*LOG2E); X1[i]=ex2((X1[i]-mx)*LOG2E); s_+=X0[i]+X1[i]; } \
    s_ = rsum16(s_); float rs_ = rcpf_(s_); \
    _Pragma("unroll") for (int i=0;i<4;i++){ X0[i]*=rs_; X1[i]*=rs_; } \
    u16* dp_ = smu + (OFFE) + er*136 + ep*4; \
    st4b(dp_, X0[0],X0[1],X0[2],X0[3]); st4b(dp_+64, X1[0],X1[1],X1[2],X1[3]); }
  SMAX(A0,A1,AS_E)
  SMAX(V0,V1,VS_E)
  SMAX(L0,L1,LS_E)
  float dav=0.f,dal=0.f,dvl=0.f;
  #pragma unroll
  for (int i=0;i<4;i++){ dav += A0[i]*V0[i]+A1[i]*V1[i]; dal += A0[i]*L0[i]+A1[i]*L1[i]; dvl += V0[i]*L0[i]+V1[i]*L1[i]; }
  dav = rsum16(dav); dal = rsum16(dal); dvl = rsum16(dvl);
  float sav = (sa+sv)*rcpf_(dav+0.5f);
  float sal = (sa+sl)*rcpf_(dal+0.5f);
  float svl = (sl+sv)*rcpf_(dvl+0.5f);
  if (ep==0){
    float mx = fmaxf(sav,fmaxf(sal,svl));
    float e0 = ex2((sav-mx)*LOG2E), e1 = ex2((sal-mx)*LOG2E), e2 = ex2((svl-mx)*LOG2E);
    float rs = rcpf_(e0+e1+e2);
    scr[er*12+0]=e0*rs; scr[er*12+1]=e1*rs; scr[er*12+2]=e2*rs;
  }
  __syncthreads();   // (1) softmaxes+scr ready

  // ================= P1: gf on 3 pairs =================
  const u16* g1t = wb;            // [64][256]
  const u16* g2t = wb + 16384;    // [128][64]
  bfrag B1[8];
  #pragma unroll
  for (int s=0;s<8;s++) B1[s] = *(const bfrag*)(g1t + (w*16+m)*256 + s*32 + q*8);
  bfrag B2[2][2];
  #pragma unroll
  for (int t=0;t<2;t++){
    #pragma unroll
    for (int s=0;s<2;s++) B2[t][s] = *(const bfrag*)(g2t + ((w+4*t)*16+m)*64 + s*32 + q*8);
  }
  facc acc0={0,0,0,0}, acc1={0,0,0,0}, acc2={0,0,0,0};
  #pragma unroll
  for (int s=0;s<8;s++){
    int k = s*32 + q*8, ko = k & 127; bool hi = (k >= 128);
    const u16* p0 = smu + (hi? VS_E:AS_E) + m*136 + ko;  // (a',v')
    const u16* p1 = smu + (hi? LS_E:AS_E) + m*136 + ko;  // (a',l')
    const u16* p2 = smu + (hi? LS_E:VS_E) + m*136 + ko;  // (v',l')
    acc0 = MFMA(*(const bfrag*)p0, B1[s], acc0);
    acc1 = MFMA(*(const bfrag*)p1, B1[s], acc1);
    acc2 = MFMA(*(const bfrag*)p2, B1[s], acc2);
  }
  { // leaky_relu -> H3 @ HH_E (stride 72)
    float b1v = gf_b1[w*16+m];
    #pragma unroll
    for (int r=0;r<4;r++){
      int rr = q*4+r;
      float h0 = acc0[r]+b1v; h0 = fmaxf(h0, 0.2f*h0);
      float h1 = acc1[r]+b1v; h1 = fmaxf(h1, 0.2f*h1);
      float h2 = acc2[r]+b1v; h2 = fmaxf(h2, 0.2f*h2);
      smu[HH_E + 0*1152 + rr*72 + w*16+m] = f2b(h0);
      smu[HH_E + 1*1152 + rr*72 + w*16+m] = f2b(h1);
      smu[HH_E + 2*1152 + rr*72 + w*16+m] = f2b(h2);
    }
  }
  __syncthreads();   // (2) H3 ready
  facc c2[3][2] = {{{0,0,0,0},{0,0,0,0}},{{0,0,0,0},{0,0,0,0}},{{0,0,0,0},{0,0,0,0}}};
  #pragma unroll
  for (int s=0;s<2;s++){
    int k = s*32 + q*8;
    #pragma unroll
    for (int p3=0;p3<3;p3++){
      bfrag Af = *(const bfrag*)(smu + HH_E + p3*1152 + m*72 + k);
      c2[p3][0] = MFMA(Af, B2[0][s], c2[p3][0]);
      c2[p3][1] = MFMA(Af, B2[1][s], c2[p3][1]);
    }
  }
  __syncthreads();   // (2b) H3 consumed — HH free for G
  float bim[2][4] = {{0,0,0,0},{0,0,0,0}};
  { // G = tanh(..) @ HH_E (stride 136), a_v/a_l/v_l = tanh(n*g), bim in regs
    float b2v0 = gf_b2[w*16+m], b2v1 = gf_b2[(w+4)*16+m];
    float nv[4][3];
    #pragma unroll
    for (int r=0;r<4;r++){ int rr=q*4+r; nv[r][0]=scr[rr*12+0]; nv[r][1]=scr[rr*12+1]; nv[r][2]=scr[rr*12+2]; }
    #pragma unroll
    for (int p3=0;p3<3;p3++){
      #pragma unroll
      for (int t=0;t<2;t++){
        float bb = t? b2v1 : b2v0;
        int cc = (w+4*t)*16+m;
        #pragma unroll
        for (int r=0;r<4;r++){
          int rr=q*4+r;
          float g = ftanh(c2[p3][t][r] + bb);
          smu[HH_E + p3*2176 + rr*136 + cc] = f2b(g);
          float tt = ftanh(nv[r][p3]*g);
          smu[AV_E + p3*2176 + rr*136 + cc] = f2b(tt);
          bim[t][r] += tt;
        }
      }
    }
  }
  __syncthreads();   // (3) G + AV/AL/VL ready

  // ================= P2: softmax stats of G, 6 dots, n2 =================
  float E0[8], E1[8], E2[8];
  #define GSTAT(EA, G3) { \
    const u16* gp_ = smu + HH_E + (G3)*2176 + er*136 + ep*4; \
    ushort4 ga_ = *(const ushort4*)gp_; ushort4 gb_ = *(const ushort4*)(gp_+64); \
    float x_[8]; \
    x_[0]=b2f(ga_.x); x_[1]=b2f(ga_.y); x_[2]=b2f(ga_.z); x_[3]=b2f(ga_.w); \
    x_[4]=b2f(gb_.x); x_[5]=b2f(gb_.y); x_[6]=b2f(gb_.z); x_[7]=b2f(gb_.w); \
    float mx_=-3.0e38f; \
    _Pragma("unroll") for (int j=0;j<8;j++) mx_=fmaxf(mx_,x_[j]); \
    mx_ = rmax16(mx_); float s_=0.f; \
    _Pragma("unroll") for (int j=0;j<8;j++){ x_[j]=ex2((x_[j]-mx_)*LOG2E); s_+=x_[j]; } \
    s_ = rsum16(s_); float rs_=rcpf_(s_); \
    _Pragma("unroll") for (int j=0;j<8;j++) EA[j]=x_[j]*rs_; }
  GSTAT(E0,0)
  GSTAT(E1,1)
  GSTAT(E2,2)
  float d01=0.f,d02=0.f,d12=0.f,d0l=0.f,d1v=0.f,d2a=0.f;
  #pragma unroll
  for (int i=0;i<4;i++){
    d01 += E0[i]*E1[i] + E0[4+i]*E1[4+i];
    d02 += E0[i]*E2[i] + E0[4+i]*E2[4+i];
    d12 += E1[i]*E2[i] + E1[4+i]*E2[4+i];
    d0l += E0[i]*L0[i] + E0[4+i]*L1[i];
    d1v += E1[i]*V0[i] + E1[4+i]*V1[i];
    d2a += E2[i]*A0[i] + E2[4+i]*A1[i];
  }
  d01=rsum16(d01); d02=rsum16(d02); d12=rsum16(d12);
  d0l=rsum16(d0l); d1v=rsum16(d1v); d2a=rsum16(d2a);
  if (ep==0){
    float x0 = (sav+svl)*rcpf_(d02+0.5f);  // savvl
    float x1 = (sav+sal)*rcpf_(d01+0.5f);  // saavl
    float x2 = (sal+svl)*rcpf_(d12+0.5f);  // savll
    float x3 = (sav+sl )*rcpf_(d0l+0.5f);  // savl
    float x4 = (sal+sv )*rcpf_(d1v+0.5f);  // salv
    float x5 = (sa +svl)*rcpf_(d2a+0.5f);  // svla
    float mx = fmaxf(fmaxf(fmaxf(x0,x1),fmaxf(x2,x3)),fmaxf(x4,x5));
    float e0=ex2((x0-mx)*LOG2E), e1=ex2((x1-mx)*LOG2E), e2=ex2((x2-mx)*LOG2E);
    float e3=ex2((x3-mx)*LOG2E), e4=ex2((x4-mx)*LOG2E), e5=ex2((x5-mx)*LOG2E);
    float rs = rcpf_(e0+e1+e2+e3+e4+e5);
    scr[er*12+3]=e0*rs; scr[er*12+4]=e1*rs; scr[er*12+5]=e2*rs;
    scr[er*12+6]=e3*rs; scr[er*12+7]=e4*rs; scr[er*12+8]=e5*rs;
  }
  __syncthreads();   // (4) G consumed (HH free for H6), n2 ready

  // ================= P3: gf2 on 6 pairs, trimodal =================
  const u16* h1t = wb + 24576;
  const u16* h2t = wb + 40960;
  bfrag C1[8];
  #pragma unroll
  for (int s=0;s<8;s++) C1[s] = *(const bfrag*)(h1t + (w*16+m)*256 + s*32 + q*8);
  bfrag C2[2][2];
  #pragma unroll
  for (int t=0;t<2;t++){
    #pragma unroll
    for (int s=0;s<2;s++) C2[t][s] = *(const bfrag*)(h2t + ((w+4*t)*16+m)*64 + s*32 + q*8);
  }
  const int S0[6] = {AV_E, AV_E, VL_E, AV_E, AL_E, VL_E};
  const int S1[6] = {VL_E, AL_E, AL_E, LS_E, VS_E, AS_E};
  facc cc1[6];
  #pragma unroll
  for (int pr=0;pr<6;pr++){ facc z = {0,0,0,0}; cc1[pr] = z; }
  #pragma unroll
  for (int s=0;s<8;s++){
    int k = s*32+q*8, ko = k&127; bool hi = (k>=128);
    #pragma unroll
    for (int pr=0;pr<6;pr++){
      const u16* sp = smu + (hi? S1[pr]:S0[pr]) + m*136 + ko;
      cc1[pr] = MFMA(*(const bfrag*)sp, C1[s], cc1[pr]);
    }
  }
  {
    float b1v = gf2_b1[w*16+m];
    #pragma unroll
    for (int pr=0;pr<6;pr++){
      #pragma unroll
      for (int r=0;r<4;r++){
        float h = cc1[pr][r]+b1v; h = fmaxf(h,0.2f*h);
        smu[HH_E + pr*1152 + (q*4+r)*72 + w*16+m] = f2b(h);  // H6
      }
    }
  }
  __syncthreads();   // (5) H6 ready; AS..VL now dead -> reusable as fusion
  facc cc2[6][2];
  #pragma unroll
  for (int pr=0;pr<6;pr++){ facc z = {0,0,0,0}; cc2[pr][0]=z; cc2[pr][1]=z; }
  #pragma unroll
  for (int s=0;s<2;s++){
    int k=s*32+q*8;
    #pragma unroll
    for (int pr=0;pr<6;pr++){
      bfrag Af = *(const bfrag*)(smu + HH_E + pr*1152 + m*72 + k);
      cc2[pr][0] = MFMA(Af, C2[0][s], cc2[pr][0]);
      cc2[pr][1] = MFMA(Af, C2[1][s], cc2[pr][1]);
    }
  }
  { // trimodal -> LS_E; bim -> VS_E; uni -> AS_E   (fusion = [uni|bim|tri])
    float b2v0 = gf2_b2[w*16+m], b2v1 = gf2_b2[(w+4)*16+m];
    float tri[2][4] = {{0,0,0,0},{0,0,0,0}};
    float n2v[4][6];
    #pragma unroll
    for (int r=0;r<4;r++){
      #pragma unroll
      for (int j=0;j<6;j++) n2v[r][j] = scr[(q*4+r)*12+3+j];
    }
    #pragma unroll
    for (int pr=0;pr<6;pr++){
      #pragma unroll
      for (int t=0;t<2;t++){
        float bb = t? b2v1 : b2v0;
        #pragma unroll
        for (int r=0;r<4;r++){
          float g = ftanh(cc2[pr][t][r] + bb);
          tri[t][r] += ftanh(n2v[r][pr]*g);
        }
      }
    }
    #pragma unroll
    for (int t=0;t<2;t++){
      #pragma unroll
      for (int r=0;r<4;r++){
        smu[LS_E + (q*4+r)*136 + (w+4*t)*16+m] = f2b(tri[t][r]);
        smu[VS_E + (q*4+r)*136 + (w+4*t)*16+m] = f2b(bim[t][r]);
      }
    }
    *(uint2*)(smu + AS_E + er*136 + ep*4)      = make_uint2(uni_pk[0], uni_pk[1]);
    *(uint2*)(smu + AS_E + er*136 + ep*4 + 64) = make_uint2(uni_pk[2], uni_pk[3]);
  }
  __syncthreads();   // (6) fusion complete (AS|VS|LS), H6 consumed

  // ================= P4: final head 384->64->64->128 =================
  const u16* lw1 = wb + 49152;
  const u16* lw2 = wb + 73728;
  const u16* lw3 = wb + 77824;
  {
    facc c = {0,0,0,0};
    #pragma unroll
    for (int s=0;s<12;s++){
      const int base = (s<4)? AS_E : (s<8)? VS_E : LS_E;
      bfrag Bf = *(const bfrag*)(lw1 + (w*16+m)*384 + s*32 + q*8);
      bfrag Af = *(const bfrag*)(smu + base + m*136 + (s&3)*32 + q*8);
      c = MFMA(Af, Bf, c);
    }
    float b = ll_b1[w*16+m];
    #pragma unroll
    for (int r=0;r<4;r++) smu[HH_E + (q*4+r)*72 + w*16+m] = f2b(ftanh(c[r]+b));
  }
  __syncthreads();   // (7)
  {
    facc c = {0,0,0,0};
    #pragma unroll
    for (int s=0;s<2;s++){
      bfrag Bf = *(const bfrag*)(lw2 + (w*16+m)*64 + s*32 + q*8);
      bfrag Af = *(const bfrag*)(smu + HH_E + m*72 + s*32 + q*8);
      c = MFMA(Af, Bf, c);
    }
    float b = ll_b2[w*16+m];
    #pragma unroll
    for (int r=0;r<4;r++) smu[HH_E + 1152 + (q*4+r)*72 + w*16+m] = f2b(ftanh(c[r]+b));
  }
  __syncthreads();   // (8)
  {
    facc c0={0,0,0,0}, c1={0,0,0,0};
    #pragma unroll
    for (int s=0;s<2;s++){
      bfrag Af  = *(const bfrag*)(smu + HH_E + 1152 + m*72 + s*32 + q*8);
      bfrag Bf0 = *(const bfrag*)(lw3 + (w*16+m)*64 + s*32 + q*8);
      bfrag Bf1 = *(const bfrag*)(lw3 + ((w+4)*16+m)*64 + s*32 + q*8);
      c0 = MFMA(Af, Bf0, c0);
      c1 = MFMA(Af, Bf1, c1);
    }
    float b0 = ll_b3[w*16+m], b1 = ll_b3[(w+4)*16+m];
    #pragma unroll
    for (int r=0;r<4;r++){
      out[(row0+q*4+r)*128 + w*16+m]        = ftanh(c0[r]+b0);
      out[(row0+q*4+r)*128 + (w+4)*16+m]    = ftanh(c1[r]+b1);
    }
  }
}

extern "C" void kernel_launch(void* const* d_in, const int* in_sizes, int n_in,
                              void* d_out, int out_size, void* d_ws, size_t ws_size,
                              hipStream_t stream)
{
  const float* l      = (const float*)d_in[0];
  const float* a      = (const float*)d_in[1];
  const float* v      = (const float*)d_in[2];
  const float* att_w  = (const float*)d_in[3];
  const float* att_b  = (const float*)d_in[4];
  const float* gf_w1  = (const float*)d_in[5];
  const float* gf_b1  = (const float*)d_in[6];
  const float* gf_w2  = (const float*)d_in[7];
  const float* gf_b2  = (const float*)d_in[8];
  const float* gf2_w1 = (const float*)d_in[9];
  const float* gf2_b1 = (const float*)d_in[10];
  const float* gf2_w2 = (const float*)d_in[11];
  const float* gf2_b2 = (const float*)d_in[12];
  const float* ll_w1  = (const float*)d_in[13];
  const float* ll_b1  = (const float*)d_in[14];
  const float* ll_w2  = (const float*)d_in[15];
  const float* ll_b2  = (const float*)d_in[16];
  const float* ll_w3  = (const float*)d_in[17];
  const float* ll_b3  = (const float*)d_in[18];
  u16* blob = (u16*)d_ws;

  prep_weights<<<336, 256, 0, stream>>>(gf_w1, gf_w2, gf2_w1, gf2_w2, ll_w1, ll_w2, ll_w3, blob);
  fused_graph<<<4096, 256, 0, stream>>>(l, a, v, att_w, att_b,
                                        gf_b1, gf_b2, gf2_b1, gf2_b2,
                                        ll_b1, ll_b2, ll_b3, blob, (float*)d_out);
}